// Round 4
// baseline (102498.425 us; speedup 1.0000x reference)
//
#include <hip/hip_runtime.h>

#define HIDDEN 512
#define TSEQ 512
#define NKEYS 128

typedef short short8_t __attribute__((ext_vector_type(8)));
typedef short short4_t __attribute__((ext_vector_type(4)));
typedef float f32x4 __attribute__((ext_vector_type(4)));

__device__ __forceinline__ ushort f2bf(float f) {
    union { float f; unsigned u; } v; v.f = f;
    unsigned r = (v.u + 0x7FFFu + ((v.u >> 16) & 1u)) >> 16;
    return (ushort)r;
}
__device__ __forceinline__ float sigm(float x) { return 1.0f / (1.0f + __expf(-x)); }
__device__ __forceinline__ float tanh_f(float x) { return 2.0f / (1.0f + __expf(-2.0f * x)) - 1.0f; }

// Plain row-major bf16 cast of [W_ih | W_hh]: Wc[row*K + k], k<KIN from Wih, else Whh.
__global__ void cast_w(const float* __restrict__ Wih, const float* __restrict__ Whh,
                       ushort* __restrict__ Wc, int KIN, int K) {
    long idx = (long)blockIdx.x * blockDim.x + threadIdx.x;
    if (idx >= (long)2048 * K) return;
    int row = (int)(idx / K), k = (int)(idx % K);
    float v = (k < KIN) ? Wih[(long)row * KIN + k] : Whh[(long)row * HIDDEN + (k - KIN)];
    Wc[idx] = f2bf(v);
}

__global__ void prep_bias(const float* __restrict__ a, const float* __restrict__ b,
                          const float* __restrict__ c, const float* __restrict__ d,
                          float* __restrict__ b0, float* __restrict__ b1) {
    int i = blockIdx.x * blockDim.x + threadIdx.x;
    if (i < 2048) { b0[i] = a[i] + b[i]; b1[i] = c[i] + d[i]; }
}

// One LSTM layer, serial over T. 16 blocks x 512 threads; block owns 16 batch rows.
// mode 0: input = x (f32 [B][T][128]), K=640, writes hout (bf16 [B][T][512]).
// mode 1: input = hin (bf16 [B][T][512]), K=1024, writes hlast (f32 [B][512]) at t=TSEQ-1.
// LDS: single buffer [16 rows][1024 units] bf16, NO swizzle. Units [0,KIN) = step input,
// units [KIN, KIN+512) = recurrent h (persists in place). Two barriers per step.
__global__ __launch_bounds__(512) void lstm_layer(
    const float* __restrict__ x, const ushort* __restrict__ hin,
    const ushort* __restrict__ Wc, const float* __restrict__ bias,
    ushort* __restrict__ hout, float* __restrict__ hlast, int mode)
{
    __shared__ __align__(16) ushort lds[16 * 1024];   // 32 KiB
    const int tid  = threadIdx.x;
    const int b0   = blockIdx.x * 16;
    const int KIN  = mode ? 512 : 128;
    const int K    = mode ? 1024 : 640;
    const int KS   = K / 32;

    const int w    = tid >> 6, lane = tid & 63;
    const int hi4  = lane >> 4;        // k-group (A and B symmetric)
    const int arow = lane & 15;        // A row-in-tile == B col (batch) == D col

    for (int i = tid; i < 16 * 1024; i += 512) lds[i] = 0;

    float c[16];
#pragma unroll
    for (int i = 0; i < 16; ++i) c[i] = 0.0f;

    const int si = tid >> 5;           // stage row 0..15
    const int sj = tid & 31;

    __syncthreads();

    for (int t = 0; t < TSEQ; ++t) {
        // ---- stage step input into units [0, KIN) ----
        if (!mode) {
            float4 v = *(const float4*)(x + (((long)(b0 + si) * TSEQ + t) * NKEYS + sj * 4));
            short4_t s;
            s[0] = (short)f2bf(v.x); s[1] = (short)f2bf(v.y);
            s[2] = (short)f2bf(v.z); s[3] = (short)f2bf(v.w);
            *(short4_t*)(lds + si * 1024 + sj * 4) = s;
        } else {
            const ushort* src = hin + ((long)(b0 + si) * TSEQ + t) * HIDDEN + sj * 16;
            *(short8_t*)(lds + si * 1024 + sj * 16)     = *(const short8_t*)src;
            *(short8_t*)(lds + si * 1024 + sj * 16 + 8) = *(const short8_t*)(src + 8);
        }
        __syncthreads();   // barrier A: staged input + prev-step h writes visible

        // ---- matmul: acc[tt] = bias + Wcat * kvec ----
        f32x4 acc[16];
#pragma unroll
        for (int tt = 0; tt < 16; ++tt) {
            int grow0 = (tt >> 2) * 512 + w * 64 + (tt & 3) * 16;
            acc[tt] = *(const f32x4*)(bias + grow0 + hi4 * 4);
        }
        for (int ks = 0; ks < KS; ++ks) {
            short8_t bfrag = *(const short8_t*)(lds + arow * 1024 + ks * 32 + hi4 * 8);
#pragma unroll
            for (int tt = 0; tt < 16; ++tt) {
                int grow0 = (tt >> 2) * 512 + w * 64 + (tt & 3) * 16;
                short8_t af = *(const short8_t*)(Wc + (size_t)(grow0 + arow) * K + ks * 32 + hi4 * 8);
                acc[tt] = __builtin_amdgcn_mfma_f32_16x16x32_bf16(af, bfrag, acc[tt], 0, 0, 0);
            }
        }
        __syncthreads();   // barrier B: all h(t-1) reads done before overwrite

        // ---- elementwise LSTM update (fp32 state in registers) ----
        // acc[tt][r] = D[row = hi4*4 + r][col = arow] of tile tt (m89 C/D layout)
#pragma unroll
        for (int sb = 0; sb < 4; ++sb) {
            float hf[4];
            short4_t hv;
#pragma unroll
            for (int r = 0; r < 4; ++r) {
                float ig = sigm(acc[sb][r]);
                float fg = sigm(acc[4 + sb][r]);
                float gg = tanh_f(acc[8 + sb][r]);
                float og = sigm(acc[12 + sb][r]);
                float cc = fg * c[sb * 4 + r] + ig * gg;
                c[sb * 4 + r] = cc;
                float h = og * tanh_f(cc);
                hf[r] = h;
                hv[r] = (short)f2bf(h);
            }
            const int u0 = w * 64 + sb * 16 + hi4 * 4;   // hidden unit base
            *(short4_t*)(lds + arow * 1024 + KIN + u0) = hv;   // recurrent h, batch=arow
            if (!mode) {
                *(short4_t*)(hout + ((long)(b0 + arow) * TSEQ + t) * HIDDEN + u0) = hv;
            } else if (t == TSEQ - 1) {
                *(float4*)(hlast + (b0 + arow) * HIDDEN + u0) =
                    make_float4(hf[0], hf[1], hf[2], hf[3]);
            }
        }
        // next iteration's barrier A orders these h writes before the next matmul
    }
}

// d_out is FLOAT32 (reference output dtype is f32) — this was the rounds-1..3 bug.
__global__ void fc_kernel(const float* __restrict__ hlast, const float* __restrict__ Wfc,
                          const float* __restrict__ bfc, float* __restrict__ out) {
    __shared__ float hs[HIDDEN];
    const int b = blockIdx.x, n = threadIdx.x;   // 128 threads
    for (int k = n; k < HIDDEN; k += 128) hs[k] = hlast[b * HIDDEN + k];
    __syncthreads();
    const float* wr = Wfc + (long)n * HIDDEN;
    float acc = bfc[n];
#pragma unroll 8
    for (int k = 0; k < HIDDEN; ++k) acc += hs[k] * wr[k];
    out[b * 128 + n] = acc;
}

extern "C" void kernel_launch(void* const* d_in, const int* in_sizes, int n_in,
                              void* d_out, int out_size, void* d_ws, size_t ws_size,
                              hipStream_t stream) {
    const float* x    = (const float*)d_in[0];
    const float* Wih0 = (const float*)d_in[1];
    const float* Whh0 = (const float*)d_in[2];
    const float* bih0 = (const float*)d_in[3];
    const float* bhh0 = (const float*)d_in[4];
    const float* Wih1 = (const float*)d_in[5];
    const float* Whh1 = (const float*)d_in[6];
    const float* bih1 = (const float*)d_in[7];
    const float* bhh1 = (const float*)d_in[8];
    const float* Wfc  = (const float*)d_in[9];
    const float* bfc  = (const float*)d_in[10];

    char* ws = (char*)d_ws;
    size_t off = 0;
    auto alloc = [&](size_t bytes) {
        void* p = ws + off;
        off = (off + bytes + 255) & ~(size_t)255;
        return p;
    };
    ushort* Wc0   = (ushort*)alloc(2048UL * 640 * 2);        // 2.62 MB
    ushort* Wc1   = (ushort*)alloc(2048UL * 1024 * 2);       // 4.19 MB
    float*  b0    = (float*)alloc(2048 * 4);
    float*  b1    = (float*)alloc(2048 * 4);
    float*  hlast = (float*)alloc(256UL * 512 * 4);          // 0.52 MB
    ushort* h0buf = (ushort*)alloc(256UL * 512 * 512 * 2);   // 134.2 MB
    if (ws_size < off) return;

    cast_w<<<(2048 * 640  + 255) / 256, 256, 0, stream>>>(Wih0, Whh0, Wc0, 128, 640);
    cast_w<<<(2048 * 1024 + 255) / 256, 256, 0, stream>>>(Wih1, Whh1, Wc1, 512, 1024);
    prep_bias<<<8, 256, 0, stream>>>(bih0, bhh0, bih1, bhh1, b0, b1);

    lstm_layer<<<16, 512, 0, stream>>>(x, nullptr, Wc0, b0, h0buf, nullptr, 0);
    lstm_layer<<<16, 512, 0, stream>>>(nullptr, h0buf, Wc1, b1, nullptr, hlast, 1);

    fc_kernel<<<256, 128, 0, stream>>>(hlast, Wfc, bfc, (float*)d_out);
}

// Round 5
// 17580.829 us; speedup vs baseline: 5.8301x; 5.8301x over previous
//
#include <hip/hip_runtime.h>

#define HIDDEN 512
#define TSEQ 512
#define NKEYS 128

typedef short short8_t __attribute__((ext_vector_type(8)));
typedef short short4_t __attribute__((ext_vector_type(4)));
typedef float f32x4 __attribute__((ext_vector_type(4)));

__device__ __forceinline__ ushort f2bf(float f) {
    union { float f; unsigned u; } v; v.f = f;
    unsigned r = (v.u + 0x7FFFu + ((v.u >> 16) & 1u)) >> 16;
    return (ushort)r;
}
__device__ __forceinline__ float sigm(float x) { return 1.0f / (1.0f + __expf(-x)); }
__device__ __forceinline__ float tanh_f(float x) { return 2.0f / (1.0f + __expf(-2.0f * x)) - 1.0f; }

__device__ __forceinline__ void async16(const void* g, void* l) {
    __builtin_amdgcn_global_load_lds((const __attribute__((address_space(1))) unsigned int*)g,
                                     (__attribute__((address_space(3))) unsigned int*)l, 16, 0, 0);
}

// Plain row-major bf16 cast of [W_ih | W_hh]: Wc[row*K + k].
__global__ void cast_w(const float* __restrict__ Wih, const float* __restrict__ Whh,
                       ushort* __restrict__ Wc, int KIN, int K) {
    long idx = (long)blockIdx.x * blockDim.x + threadIdx.x;
    if (idx >= (long)2048 * K) return;
    int row = (int)(idx / K), k = (int)(idx % K);
    float v = (k < KIN) ? Wih[(long)row * KIN + k] : Whh[(long)row * HIDDEN + (k - KIN)];
    Wc[idx] = f2bf(v);
}

__global__ void prep_bias(const float* __restrict__ a, const float* __restrict__ b,
                          const float* __restrict__ c, const float* __restrict__ d,
                          float* __restrict__ b0, float* __restrict__ b1) {
    int i = blockIdx.x * blockDim.x + threadIdx.x;
    if (i < 2048) { b0[i] = a[i] + b[i]; b1[i] = c[i] + d[i]; }
}

// Zero h0buf slot 0 (h(-1) for L0) and h1par parity 0 (h(-1) for L1).
__global__ void init_zeros(ushort* __restrict__ h0buf, ushort* __restrict__ h1par) {
    int idx = blockIdx.x * blockDim.x + threadIdx.x;   // 65536 threads, ushort4 each
    ushort4 z = {0, 0, 0, 0};
    if (idx < 32768) {
        int b = idx >> 7, off = (idx & 127) * 4;
        *(ushort4*)(h0buf + (size_t)b * 513 * 512 + off) = z;
    } else {
        int j = idx - 32768;
        *(ushort4*)(h1par + (size_t)j * 4) = z;
    }
}

// Weight-stationary LSTM phase. Cooperative, grid=256 (1 block/CU), block=512.
// Block (tile, g): tile = batch tile (16 rows), g = gate-slice (32 hidden units).
// Wave w owns 16 gate rows: A-tile position p -> global row 512*(p&3) + Uw + (p>>2),
// Uw = g*32 + w*4. Lane (hi4, arow): unit Uw+hi4, batch b0+arow, acc[r] = gate r.
// Weights in VGPRs (af[KS], loaded once). Step input staged to LDS rows [16][K+8pad].
// MODE 0: K=640 (x 128 | rec h0 512); writes h0buf[b][t+1][u].
// MODE 1: K=1024 (h0 512 | rec h1 512); writes h1par[(t+1)&1][b][u], hlast at t=511.
template <int MODE>
__global__ __launch_bounds__(512, 2) void lstm_phase(
    const float* __restrict__ x, const ushort* __restrict__ Wc,
    const float* __restrict__ biasc, ushort* __restrict__ h0buf,
    ushort* __restrict__ h1par, float* __restrict__ hlast,
    int* __restrict__ flags)
{
    constexpr int K  = MODE ? 1024 : 640;
    constexpr int KS = K / 32;
    constexpr int RS = K + 8;                       // row stride (ushorts); +16B pad kills bank conflicts
    __shared__ __align__(16) ushort lds[16 * RS];

    const int tid = threadIdx.x, bid = blockIdx.x;
    const int tile = (bid & 7) * 2 + (bid >> 7);    // 16 blocks of a tile share an XCD (bid%8)
    const int g    = (bid >> 3) & 15;
    const int b0   = tile * 16;
    const int w = tid >> 6, lane = tid & 63, hi4 = lane >> 4, arow = lane & 15;
    const int Uw = g * 32 + w * 4;
    const int row_l = 512 * (arow & 3) + Uw + (arow >> 2);
    int* cnt = flags + (MODE ? 16 : 0) + tile;

    // ---- weights -> VGPRs (once) ----
    short8_t af[KS];
    {
        const ushort* wsrc = Wc + (size_t)row_l * K + hi4 * 8;
#pragma unroll
        for (int ks = 0; ks < KS; ++ks) af[ks] = *(const short8_t*)(wsrc + ks * 32);
    }
    f32x4 bias4;
#pragma unroll
    for (int r = 0; r < 4; ++r) bias4[r] = biasc[512 * r + Uw + hi4];

    float c = 0.0f;
    const int r0 = w * 2, r1 = r0 + 1;              // LDS rows this wave stages
    char* const buf = (char*)lds;

#pragma unroll 1
    for (int t = 0; t < TSEQ; ++t) {
        // ---- S1: independent half (no flag needed) ----
        if (MODE == 0) {
            const int si = tid >> 5, sj = tid & 31;
            float4 v = *(const float4*)(x + (((size_t)(b0 + si)) * TSEQ + t) * NKEYS + sj * 4);
            short4_t s;
            s[0] = (short)f2bf(v.x); s[1] = (short)f2bf(v.y);
            s[2] = (short)f2bf(v.z); s[3] = (short)f2bf(v.w);
            *(short4_t*)(buf + si * (RS * 2) + sj * 8) = s;
        } else {
            async16(h0buf + ((size_t)(b0 + r0) * 513 + (t + 1)) * 512 + lane * 8, buf + r0 * (RS * 2));
            async16(h0buf + ((size_t)(b0 + r1) * 513 + (t + 1)) * 512 + lane * 8, buf + r1 * (RS * 2));
        }

        // ---- S2: wait for all 16 blocks' h(t-1) ----
        if (tid == 0) {
            while (__hip_atomic_load(cnt, __ATOMIC_ACQUIRE, __HIP_MEMORY_SCOPE_AGENT) < 16 * t)
                __builtin_amdgcn_s_sleep(1);
        }
        __syncthreads();   // B1

        // ---- S3: recurrent half ----
        if (MODE == 0) {
            async16(h0buf + ((size_t)(b0 + r0) * 513 + t) * 512 + lane * 8, buf + r0 * (RS * 2) + 256);
            async16(h0buf + ((size_t)(b0 + r1) * 513 + t) * 512 + lane * 8, buf + r1 * (RS * 2) + 256);
        } else {
            async16(h1par + ((size_t)(t & 1) * 256 + b0 + r0) * 512 + lane * 8, buf + r0 * (RS * 2) + 1024);
            async16(h1par + ((size_t)(t & 1) * 256 + b0 + r1) * 512 + lane * 8, buf + r1 * (RS * 2) + 1024);
        }
        asm volatile("s_waitcnt vmcnt(0)" ::: "memory");
        __syncthreads();   // B2: all 16 rows staged

        // ---- S5: MFMA sweep (weights from VGPRs, B from LDS) ----
        f32x4 acc = bias4;
        const char* bp = buf + arow * (RS * 2) + hi4 * 16;
#pragma unroll
        for (int ks = 0; ks < KS; ++ks) {
            short8_t bf = *(const short8_t*)(bp + ks * 64);
            acc = __builtin_amdgcn_mfma_f32_16x16x32_bf16(af[ks], bf, acc, 0, 0, 0);
        }

        // ---- S6: elementwise (1 unit/lane) + publish h ----
        float ig = sigm(acc[0]), fg = sigm(acc[1]);
        float gg = tanh_f(acc[2]), og = sigm(acc[3]);
        c = fg * c + ig * gg;
        float h = og * tanh_f(c);
        int hv = f2bf(h);
        int v0 = __shfl(hv, arow, 64),      v1 = __shfl(hv, arow + 16, 64);
        int v2 = __shfl(hv, arow + 32, 64), v3 = __shfl(hv, arow + 48, 64);
        if (hi4 == 0) {
            ushort4 pk = { (ushort)v0, (ushort)v1, (ushort)v2, (ushort)v3 };
            if (MODE == 0)
                *(ushort4*)(h0buf + ((size_t)(b0 + arow) * 513 + (t + 1)) * 512 + Uw) = pk;
            else
                *(ushort4*)(h1par + ((size_t)((t + 1) & 1) * 256 + b0 + arow) * 512 + Uw) = pk;
        }
        if (MODE == 1 && t == TSEQ - 1)
            hlast[(size_t)(b0 + arow) * 512 + Uw + hi4] = h;

        asm volatile("s_waitcnt vmcnt(0)" ::: "memory");
        __syncthreads();   // B3: all waves' stores drained
        if (tid == 0)
            __hip_atomic_fetch_add(cnt, 1, __ATOMIC_RELEASE, __HIP_MEMORY_SCOPE_AGENT);
    }
}

__global__ void fc_kernel(const float* __restrict__ hlast, const float* __restrict__ Wfc,
                          const float* __restrict__ bfc, float* __restrict__ out) {
    __shared__ float hs[HIDDEN];
    const int b = blockIdx.x, n = threadIdx.x;   // 128 threads
    for (int k = n; k < HIDDEN; k += 128) hs[k] = hlast[b * HIDDEN + k];
    __syncthreads();
    const float* wr = Wfc + (long)n * HIDDEN;
    float acc = bfc[n];
#pragma unroll 8
    for (int k = 0; k < HIDDEN; ++k) acc += hs[k] * wr[k];
    out[b * 128 + n] = acc;
}

extern "C" void kernel_launch(void* const* d_in, const int* in_sizes, int n_in,
                              void* d_out, int out_size, void* d_ws, size_t ws_size,
                              hipStream_t stream) {
    const float* x    = (const float*)d_in[0];
    const float* Wih0 = (const float*)d_in[1];
    const float* Whh0 = (const float*)d_in[2];
    const float* bih0 = (const float*)d_in[3];
    const float* bhh0 = (const float*)d_in[4];
    const float* Wih1 = (const float*)d_in[5];
    const float* Whh1 = (const float*)d_in[6];
    const float* bih1 = (const float*)d_in[7];
    const float* bhh1 = (const float*)d_in[8];
    const float* Wfc  = (const float*)d_in[9];
    const float* bfc  = (const float*)d_in[10];

    char* ws = (char*)d_ws;
    size_t off = 0;
    auto alloc = [&](size_t bytes) {
        void* p = ws + off;
        off = (off + bytes + 255) & ~(size_t)255;
        return p;
    };
    ushort* Wc0   = (ushort*)alloc(2048UL * 640 * 2);         // 2.62 MB
    ushort* Wc1   = (ushort*)alloc(2048UL * 1024 * 2);        // 4.19 MB
    float*  bg0   = (float*)alloc(2048 * 4);
    float*  bg1   = (float*)alloc(2048 * 4);
    float*  hlast = (float*)alloc(256UL * 512 * 4);           // 0.52 MB
    ushort* h1par = (ushort*)alloc(2UL * 256 * 512 * 2);      // 0.52 MB
    int*    flags = (int*)alloc(256);
    ushort* h0buf = (ushort*)alloc(256UL * 513 * 512 * 2);    // 134.5 MB
    if (ws_size < off) return;

    hipMemsetAsync(flags, 0, 256, stream);
    init_zeros<<<256, 256, 0, stream>>>(h0buf, h1par);
    cast_w<<<(2048 * 640  + 255) / 256, 256, 0, stream>>>(Wih0, Whh0, Wc0, 128, 640);
    cast_w<<<(2048 * 1024 + 255) / 256, 256, 0, stream>>>(Wih1, Whh1, Wc1, 512, 1024);
    prep_bias<<<8, 256, 0, stream>>>(bih0, bhh0, bih1, bhh1, bg0, bg1);

    {
        void* args0[] = { (void*)&x, (void*)&Wc0, (void*)&bg0, (void*)&h0buf,
                          (void*)&h1par, (void*)&hlast, (void*)&flags };
        hipLaunchCooperativeKernel((const void*)lstm_phase<0>, dim3(256), dim3(512),
                                   args0, 0, stream);
    }
    {
        void* args1[] = { (void*)&x, (void*)&Wc1, (void*)&bg1, (void*)&h0buf,
                          (void*)&h1par, (void*)&hlast, (void*)&flags };
        hipLaunchCooperativeKernel((const void*)lstm_phase<1>, dim3(256), dim3(512),
                                   args1, 0, stream);
    }

    fc_kernel<<<256, 128, 0, stream>>>(hlast, Wfc, bfc, (float*)d_out);
}

// Round 6
// 17533.717 us; speedup vs baseline: 5.8458x; 1.0027x over previous
//
#include <hip/hip_runtime.h>

#define HIDDEN 512
#define TSEQ 512
#define NKEYS 128

typedef short short8_t __attribute__((ext_vector_type(8)));
typedef short short4_t __attribute__((ext_vector_type(4)));
typedef float f32x4 __attribute__((ext_vector_type(4)));

__device__ __forceinline__ ushort f2bf(float f) {
    union { float f; unsigned u; } v; v.f = f;
    unsigned r = (v.u + 0x7FFFu + ((v.u >> 16) & 1u)) >> 16;
    return (ushort)r;
}
__device__ __forceinline__ float sigm(float x) { return 1.0f / (1.0f + __expf(-x)); }
__device__ __forceinline__ float tanh_f(float x) { return 2.0f / (1.0f + __expf(-2.0f * x)) - 1.0f; }

__device__ __forceinline__ void async16(const void* g, void* l) {
    __builtin_amdgcn_global_load_lds((const __attribute__((address_space(1))) unsigned int*)g,
                                     (__attribute__((address_space(3))) unsigned int*)l, 16, 0, 0);
}

// Plain row-major bf16 cast of [W_ih | W_hh]: Wc[row*K + k].
__global__ void cast_w(const float* __restrict__ Wih, const float* __restrict__ Whh,
                       ushort* __restrict__ Wc, int KIN, int K) {
    long idx = (long)blockIdx.x * blockDim.x + threadIdx.x;
    if (idx >= (long)2048 * K) return;
    int row = (int)(idx / K), k = (int)(idx % K);
    float v = (k < KIN) ? Wih[(long)row * KIN + k] : Whh[(long)row * HIDDEN + (k - KIN)];
    Wc[idx] = f2bf(v);
}

__global__ void prep_bias(const float* __restrict__ a, const float* __restrict__ b,
                          const float* __restrict__ c, const float* __restrict__ d,
                          float* __restrict__ b0, float* __restrict__ b1) {
    int i = blockIdx.x * blockDim.x + threadIdx.x;
    if (i < 2048) { b0[i] = a[i] + b[i]; b1[i] = c[i] + d[i]; }
}

// Zero h0buf slot 0 (h(-1) for L0) and h1par parity 0 (h(-1) for L1).
__global__ void init_zeros(ushort* __restrict__ h0buf, ushort* __restrict__ h1par) {
    int idx = blockIdx.x * blockDim.x + threadIdx.x;   // 65536 threads, ushort4 each
    ushort4 z = {0, 0, 0, 0};
    if (idx < 32768) {
        int b = idx >> 7, off = (idx & 127) * 4;
        *(ushort4*)(h0buf + (size_t)b * 513 * 512 + off) = z;
    } else {
        int j = idx - 32768;
        *(ushort4*)(h1par + (size_t)j * 4) = z;
    }
}

// Weight-stationary LSTM phase. Cooperative, grid=256 (1 block/CU), block=512.
// Block (tile, g): tile = batch tile (16 rows), g = gate-slice (32 hidden units).
// Wave w owns 16 gate rows: A-tile position p -> global row 512*(p&3) + Uw + (p>>2),
// Uw = g*32 + w*4. Lane (hi4, arow): unit Uw+hi4, batch b0+arow, acc[r] = gate r.
// Weights in VGPRs (af[KS], loaded once). Step input staged to LDS rows [16][K+8pad].
// MODE 0: K=640 (x 128 | rec h0 512); writes h0buf[b][t+1][u].
// MODE 1: K=1024 (h0 512 | rec h1 512); writes h1par[(t+1)&1][b][u], hlast at t=511.
// NOTE: __launch_bounds__(512, 1) — round-5's (512,2) clamped VGPRs to 64 and
// spilled af[] to scratch (VGPR_Count=64, FETCH 114MB/dispatch). 1 block/CU is
// all we need; allocator may use up to 256 arch VGPRs.
template <int MODE>
__global__ __launch_bounds__(512, 1) void lstm_phase(
    const float* __restrict__ x, const ushort* __restrict__ Wc,
    const float* __restrict__ biasc, ushort* __restrict__ h0buf,
    ushort* __restrict__ h1par, float* __restrict__ hlast,
    int* __restrict__ flags)
{
    constexpr int K  = MODE ? 1024 : 640;
    constexpr int KS = K / 32;
    constexpr int RS = K + 8;                       // row stride (ushorts); +16B pad spreads banks
    __shared__ __align__(16) ushort lds[16 * RS];

    const int tid = threadIdx.x, bid = blockIdx.x;
    const int tile = (bid & 7) * 2 + (bid >> 7);    // 16 blocks of a tile share an XCD (bid%8)
    const int g    = (bid >> 3) & 15;
    const int b0   = tile * 16;
    const int w = tid >> 6, lane = tid & 63, hi4 = lane >> 4, arow = lane & 15;
    const int Uw = g * 32 + w * 4;
    const int row_l = 512 * (arow & 3) + Uw + (arow >> 2);
    int* cnt = flags + (MODE ? 16 : 0) + tile;

    // ---- weights -> VGPRs (once) ----
    short8_t af[KS];
    {
        const ushort* wsrc = Wc + (size_t)row_l * K + hi4 * 8;
#pragma unroll
        for (int ks = 0; ks < KS; ++ks) af[ks] = *(const short8_t*)(wsrc + ks * 32);
    }
    f32x4 bias4;
#pragma unroll
    for (int r = 0; r < 4; ++r) bias4[r] = biasc[512 * r + Uw + hi4];

    float c = 0.0f;
    const int r0 = w * 2, r1 = r0 + 1;              // LDS rows this wave stages
    char* const buf = (char*)lds;

#pragma unroll 1
    for (int t = 0; t < TSEQ; ++t) {
        // ---- S1: independent half (no flag needed) ----
        if (MODE == 0) {
            const int si = tid >> 5, sj = tid & 31;
            float4 v = *(const float4*)(x + (((size_t)(b0 + si)) * TSEQ + t) * NKEYS + sj * 4);
            short4_t s;
            s[0] = (short)f2bf(v.x); s[1] = (short)f2bf(v.y);
            s[2] = (short)f2bf(v.z); s[3] = (short)f2bf(v.w);
            *(short4_t*)(buf + si * (RS * 2) + sj * 8) = s;
        } else {
            async16(h0buf + ((size_t)(b0 + r0) * 513 + (t + 1)) * 512 + lane * 8, buf + r0 * (RS * 2));
            async16(h0buf + ((size_t)(b0 + r1) * 513 + (t + 1)) * 512 + lane * 8, buf + r1 * (RS * 2));
        }

        // ---- S2: wait for all 16 blocks' h(t-1) ----
        if (tid == 0) {
            while (__hip_atomic_load(cnt, __ATOMIC_ACQUIRE, __HIP_MEMORY_SCOPE_AGENT) < 16 * t)
                __builtin_amdgcn_s_sleep(1);
        }
        __syncthreads();   // B1

        // ---- S3: recurrent half ----
        if (MODE == 0) {
            async16(h0buf + ((size_t)(b0 + r0) * 513 + t) * 512 + lane * 8, buf + r0 * (RS * 2) + 256);
            async16(h0buf + ((size_t)(b0 + r1) * 513 + t) * 512 + lane * 8, buf + r1 * (RS * 2) + 256);
        } else {
            async16(h1par + ((size_t)(t & 1) * 256 + b0 + r0) * 512 + lane * 8, buf + r0 * (RS * 2) + 1024);
            async16(h1par + ((size_t)(t & 1) * 256 + b0 + r1) * 512 + lane * 8, buf + r1 * (RS * 2) + 1024);
        }
        asm volatile("s_waitcnt vmcnt(0)" ::: "memory");
        __syncthreads();   // B2: all 16 rows staged

        // ---- S5: MFMA sweep (weights from VGPRs, B from LDS) ----
        f32x4 acc = bias4;
        const char* bp = buf + arow * (RS * 2) + hi4 * 16;
#pragma unroll
        for (int ks = 0; ks < KS; ++ks) {
            short8_t bf = *(const short8_t*)(bp + ks * 64);
            acc = __builtin_amdgcn_mfma_f32_16x16x32_bf16(af[ks], bf, acc, 0, 0, 0);
        }

        // ---- S6: elementwise (1 unit/lane) + publish h ----
        float ig = sigm(acc[0]), fg = sigm(acc[1]);
        float gg = tanh_f(acc[2]), og = sigm(acc[3]);
        c = fg * c + ig * gg;
        float h = og * tanh_f(c);
        int hv = f2bf(h);
        int v0 = __shfl(hv, arow, 64),      v1 = __shfl(hv, arow + 16, 64);
        int v2 = __shfl(hv, arow + 32, 64), v3 = __shfl(hv, arow + 48, 64);
        if (hi4 == 0) {
            ushort4 pk = { (ushort)v0, (ushort)v1, (ushort)v2, (ushort)v3 };
            if (MODE == 0)
                *(ushort4*)(h0buf + ((size_t)(b0 + arow) * 513 + (t + 1)) * 512 + Uw) = pk;
            else
                *(ushort4*)(h1par + ((size_t)((t + 1) & 1) * 256 + b0 + arow) * 512 + Uw) = pk;
        }
        if (MODE == 1 && t == TSEQ - 1)
            hlast[(size_t)(b0 + arow) * 512 + Uw + hi4] = h;

        asm volatile("s_waitcnt vmcnt(0)" ::: "memory");
        __syncthreads();   // B3: all waves' stores drained
        if (tid == 0)
            __hip_atomic_fetch_add(cnt, 1, __ATOMIC_RELEASE, __HIP_MEMORY_SCOPE_AGENT);
    }
}

__global__ void fc_kernel(const float* __restrict__ hlast, const float* __restrict__ Wfc,
                          const float* __restrict__ bfc, float* __restrict__ out) {
    __shared__ float hs[HIDDEN];
    const int b = blockIdx.x, n = threadIdx.x;   // 128 threads
    for (int k = n; k < HIDDEN; k += 128) hs[k] = hlast[b * HIDDEN + k];
    __syncthreads();
    const float* wr = Wfc + (long)n * HIDDEN;
    float acc = bfc[n];
#pragma unroll 8
    for (int k = 0; k < HIDDEN; ++k) acc += hs[k] * wr[k];
    out[b * 128 + n] = acc;
}

extern "C" void kernel_launch(void* const* d_in, const int* in_sizes, int n_in,
                              void* d_out, int out_size, void* d_ws, size_t ws_size,
                              hipStream_t stream) {
    const float* x    = (const float*)d_in[0];
    const float* Wih0 = (const float*)d_in[1];
    const float* Whh0 = (const float*)d_in[2];
    const float* bih0 = (const float*)d_in[3];
    const float* bhh0 = (const float*)d_in[4];
    const float* Wih1 = (const float*)d_in[5];
    const float* Whh1 = (const float*)d_in[6];
    const float* bih1 = (const float*)d_in[7];
    const float* bhh1 = (const float*)d_in[8];
    const float* Wfc  = (const float*)d_in[9];
    const float* bfc  = (const float*)d_in[10];

    char* ws = (char*)d_ws;
    size_t off = 0;
    auto alloc = [&](size_t bytes) {
        void* p = ws + off;
        off = (off + bytes + 255) & ~(size_t)255;
        return p;
    };
    ushort* Wc0   = (ushort*)alloc(2048UL * 640 * 2);         // 2.62 MB
    ushort* Wc1   = (ushort*)alloc(2048UL * 1024 * 2);        // 4.19 MB
    float*  bg0   = (float*)alloc(2048 * 4);
    float*  bg1   = (float*)alloc(2048 * 4);
    float*  hlast = (float*)alloc(256UL * 512 * 4);           // 0.52 MB
    ushort* h1par = (ushort*)alloc(2UL * 256 * 512 * 2);      // 0.52 MB
    int*    flags = (int*)alloc(256);
    ushort* h0buf = (ushort*)alloc(256UL * 513 * 512 * 2);    // 134.5 MB
    if (ws_size < off) return;

    hipMemsetAsync(flags, 0, 256, stream);
    init_zeros<<<256, 256, 0, stream>>>(h0buf, h1par);
    cast_w<<<(2048 * 640  + 255) / 256, 256, 0, stream>>>(Wih0, Whh0, Wc0, 128, 640);
    cast_w<<<(2048 * 1024 + 255) / 256, 256, 0, stream>>>(Wih1, Whh1, Wc1, 512, 1024);
    prep_bias<<<8, 256, 0, stream>>>(bih0, bhh0, bih1, bhh1, bg0, bg1);

    {
        void* args0[] = { (void*)&x, (void*)&Wc0, (void*)&bg0, (void*)&h0buf,
                          (void*)&h1par, (void*)&hlast, (void*)&flags };
        hipLaunchCooperativeKernel((const void*)lstm_phase<0>, dim3(256), dim3(512),
                                   args0, 0, stream);
    }
    {
        void* args1[] = { (void*)&x, (void*)&Wc1, (void*)&bg1, (void*)&h0buf,
                          (void*)&h1par, (void*)&hlast, (void*)&flags };
        hipLaunchCooperativeKernel((const void*)lstm_phase<1>, dim3(256), dim3(512),
                                   args1, 0, stream);
    }

    fc_kernel<<<256, 128, 0, stream>>>(hlast, Wfc, bfc, (float*)d_out);
}

// Round 7
// 16806.841 us; speedup vs baseline: 6.0986x; 1.0432x over previous
//
#include <hip/hip_runtime.h>

#define HIDDEN 512
#define TSEQ 512
#define NKEYS 128

typedef short short8_t __attribute__((ext_vector_type(8)));
typedef short short4_t __attribute__((ext_vector_type(4)));
typedef float f32x4 __attribute__((ext_vector_type(4)));

__device__ __forceinline__ ushort f2bf(float f) {
    union { float f; unsigned u; } v; v.f = f;
    unsigned r = (v.u + 0x7FFFu + ((v.u >> 16) & 1u)) >> 16;
    return (ushort)r;
}
__device__ __forceinline__ float sigm(float x) { return 1.0f / (1.0f + __expf(-x)); }
__device__ __forceinline__ float tanh_f(float x) { return 2.0f / (1.0f + __expf(-2.0f * x)) - 1.0f; }

__device__ __forceinline__ void async16(const void* g, void* l) {
    __builtin_amdgcn_global_load_lds((const __attribute__((address_space(1))) unsigned int*)g,
                                     (__attribute__((address_space(3))) unsigned int*)l, 16, 0, 0);
}

// Plain row-major bf16 cast of [W_ih | W_hh]: Wc[row*K + k].
__global__ void cast_w(const float* __restrict__ Wih, const float* __restrict__ Whh,
                       ushort* __restrict__ Wc, int KIN, int K) {
    long idx = (long)blockIdx.x * blockDim.x + threadIdx.x;
    if (idx >= (long)2048 * K) return;
    int row = (int)(idx / K), k = (int)(idx % K);
    float v = (k < KIN) ? Wih[(long)row * KIN + k] : Whh[(long)row * HIDDEN + (k - KIN)];
    Wc[idx] = f2bf(v);
}

__global__ void prep_bias(const float* __restrict__ a, const float* __restrict__ b,
                          const float* __restrict__ c, const float* __restrict__ d,
                          float* __restrict__ b0, float* __restrict__ b1) {
    int i = blockIdx.x * blockDim.x + threadIdx.x;
    if (i < 2048) { b0[i] = a[i] + b[i]; b1[i] = c[i] + d[i]; }
}

// Zero h0buf slot 0 (h(-1) for L0) and h1par parity 0 (h(-1) for L1).
__global__ void init_zeros(ushort* __restrict__ h0buf, ushort* __restrict__ h1par) {
    int idx = blockIdx.x * blockDim.x + threadIdx.x;   // 65536 threads, ushort4 each
    ushort4 z = {0, 0, 0, 0};
    if (idx < 32768) {
        int b = idx >> 7, off = (idx & 127) * 4;
        *(ushort4*)(h0buf + (size_t)b * 513 * 512 + off) = z;
    } else {
        int j = idx - 32768;
        *(ushort4*)(h1par + (size_t)j * 4) = z;
    }
}

// ---- named weight registers: SROA refuses to promote short8_t af[32] (1 KiB
// private array -> scratch, rounds 5-6: VGPR_Count 64/92, FETCH 114MB/dispatch).
// Individually named SSA variables bypass SROA entirely. ----
#define AF_LIST_20(M) M(0)M(1)M(2)M(3)M(4)M(5)M(6)M(7)M(8)M(9)M(10)M(11)M(12)M(13)M(14)M(15)M(16)M(17)M(18)M(19)
#define AF_LIST_32(M) AF_LIST_20(M) M(20)M(21)M(22)M(23)M(24)M(25)M(26)M(27)M(28)M(29)M(30)M(31)

#define AF_DECL(i) short8_t af##i;
#define AF_LOAD(i) af##i = *(const short8_t*)(wsrc + (i) * 32);
#define AF_MFMA(i) { short8_t bf = *(const short8_t*)(bp + (i) * 64);                      \
    if ((i) & 1) acc1 = __builtin_amdgcn_mfma_f32_16x16x32_bf16(af##i, bf, acc1, 0, 0, 0); \
    else         acc0 = __builtin_amdgcn_mfma_f32_16x16x32_bf16(af##i, bf, acc0, 0, 0, 0); }

// Weight-stationary LSTM phase. Cooperative, grid=256 (1 block/CU), block=512.
// Block (tile, g): tile = batch tile (16 rows), g = gate-slice (32 hidden units).
// Wave w owns 16 gate rows: A-tile position p -> global row 512*(p&3) + Uw + (p>>2),
// Uw = g*32 + w*4. Lane (hi4, arow): unit Uw+hi4, batch b0+arow, acc[r] = gate r.
// Weights in named VGPRs (loaded once). Step input staged to LDS rows [16][K+8pad].
// MODE 0: K=640 (x 128 | rec h0 512); writes h0buf[b][t+1][u].
// MODE 1: K=1024 (h0 512 | rec h1 512); writes h1par[(t+1)&1][b][u], hlast at t=511.
template <int MODE>
__global__ __launch_bounds__(512, 1) void lstm_phase(
    const float* __restrict__ x, const ushort* __restrict__ Wc,
    const float* __restrict__ biasc, ushort* __restrict__ h0buf,
    ushort* __restrict__ h1par, float* __restrict__ hlast,
    int* __restrict__ flags)
{
    constexpr int K  = MODE ? 1024 : 640;
    constexpr int RS = K + 8;                       // row stride (ushorts); +16B pad spreads banks
    __shared__ __align__(16) ushort lds[16 * RS];

    const int tid = threadIdx.x, bid = blockIdx.x;
    const int tile = (bid & 7) * 2 + (bid >> 7);    // 16 blocks of a tile share an XCD (bid%8)
    const int g    = (bid >> 3) & 15;
    const int b0   = tile * 16;
    const int w = tid >> 6, lane = tid & 63, hi4 = lane >> 4, arow = lane & 15;
    const int Uw = g * 32 + w * 4;
    const int row_l = 512 * (arow & 3) + Uw + (arow >> 2);
    int* cnt = flags + (MODE ? 16 : 0) + tile;

    // ---- weights -> named VGPRs (once) ----
    AF_LIST_32(AF_DECL)
    {
        const ushort* wsrc = Wc + (size_t)row_l * K + hi4 * 8;
        if constexpr (MODE == 0) { AF_LIST_20(AF_LOAD) }
        else                     { AF_LIST_32(AF_LOAD) }
    }
    f32x4 bias4;
#pragma unroll
    for (int r = 0; r < 4; ++r) bias4[r] = biasc[512 * r + Uw + hi4];

    float c = 0.0f;
    const int r0 = w * 2, r1 = r0 + 1;              // LDS rows this wave stages
    char* const buf = (char*)lds;

#pragma unroll 1
    for (int t = 0; t < TSEQ; ++t) {
        // ---- S1: independent half (no flag needed) ----
        if (MODE == 0) {
            const int si = tid >> 5, sj = tid & 31;
            float4 v = *(const float4*)(x + (((size_t)(b0 + si)) * TSEQ + t) * NKEYS + sj * 4);
            short4_t s;
            s[0] = (short)f2bf(v.x); s[1] = (short)f2bf(v.y);
            s[2] = (short)f2bf(v.z); s[3] = (short)f2bf(v.w);
            *(short4_t*)(buf + si * (RS * 2) + sj * 8) = s;
        } else {
            async16(h0buf + ((size_t)(b0 + r0) * 513 + (t + 1)) * 512 + lane * 8, buf + r0 * (RS * 2));
            async16(h0buf + ((size_t)(b0 + r1) * 513 + (t + 1)) * 512 + lane * 8, buf + r1 * (RS * 2));
        }

        // ---- S2: wait for all 16 blocks' h(t-1) ----
        if (tid == 0) {
            while (__hip_atomic_load(cnt, __ATOMIC_ACQUIRE, __HIP_MEMORY_SCOPE_AGENT) < 16 * t)
                __builtin_amdgcn_s_sleep(1);
        }
        __syncthreads();   // B1

        // ---- S3: recurrent half ----
        if (MODE == 0) {
            async16(h0buf + ((size_t)(b0 + r0) * 513 + t) * 512 + lane * 8, buf + r0 * (RS * 2) + 256);
            async16(h0buf + ((size_t)(b0 + r1) * 513 + t) * 512 + lane * 8, buf + r1 * (RS * 2) + 256);
        } else {
            async16(h1par + ((size_t)(t & 1) * 256 + b0 + r0) * 512 + lane * 8, buf + r0 * (RS * 2) + 1024);
            async16(h1par + ((size_t)(t & 1) * 256 + b0 + r1) * 512 + lane * 8, buf + r1 * (RS * 2) + 1024);
        }
        asm volatile("s_waitcnt vmcnt(0)" ::: "memory");
        __syncthreads();   // B2: all 16 rows staged

        // ---- S5: MFMA sweep (weights from named VGPRs, B from LDS) ----
        f32x4 acc0 = bias4;
        f32x4 acc1 = {0.0f, 0.0f, 0.0f, 0.0f};
        const char* bp = buf + arow * (RS * 2) + hi4 * 16;
        if constexpr (MODE == 0) { AF_LIST_20(AF_MFMA) }
        else                     { AF_LIST_32(AF_MFMA) }
        f32x4 acc = acc0 + acc1;

        // ---- S6: elementwise (1 unit/lane) + publish h ----
        float ig = sigm(acc[0]), fg = sigm(acc[1]);
        float gg = tanh_f(acc[2]), og = sigm(acc[3]);
        c = fg * c + ig * gg;
        float h = og * tanh_f(c);
        int hv = f2bf(h);
        int v0 = __shfl(hv, arow, 64),      v1 = __shfl(hv, arow + 16, 64);
        int v2 = __shfl(hv, arow + 32, 64), v3 = __shfl(hv, arow + 48, 64);
        if (hi4 == 0) {
            ushort4 pk = { (ushort)v0, (ushort)v1, (ushort)v2, (ushort)v3 };
            if (MODE == 0)
                *(ushort4*)(h0buf + ((size_t)(b0 + arow) * 513 + (t + 1)) * 512 + Uw) = pk;
            else
                *(ushort4*)(h1par + ((size_t)((t + 1) & 1) * 256 + b0 + arow) * 512 + Uw) = pk;
        }
        if (MODE == 1 && t == TSEQ - 1)
            hlast[(size_t)(b0 + arow) * 512 + Uw + hi4] = h;

        asm volatile("s_waitcnt vmcnt(0)" ::: "memory");
        __syncthreads();   // B3: all waves' stores drained
        if (tid == 0)
            __hip_atomic_fetch_add(cnt, 1, __ATOMIC_RELEASE, __HIP_MEMORY_SCOPE_AGENT);
    }
}

__global__ void fc_kernel(const float* __restrict__ hlast, const float* __restrict__ Wfc,
                          const float* __restrict__ bfc, float* __restrict__ out) {
    __shared__ float hs[HIDDEN];
    const int b = blockIdx.x, n = threadIdx.x;   // 128 threads
    for (int k = n; k < HIDDEN; k += 128) hs[k] = hlast[b * HIDDEN + k];
    __syncthreads();
    const float* wr = Wfc + (long)n * HIDDEN;
    float acc = bfc[n];
#pragma unroll 8
    for (int k = 0; k < HIDDEN; ++k) acc += hs[k] * wr[k];
    out[b * 128 + n] = acc;
}

extern "C" void kernel_launch(void* const* d_in, const int* in_sizes, int n_in,
                              void* d_out, int out_size, void* d_ws, size_t ws_size,
                              hipStream_t stream) {
    const float* x    = (const float*)d_in[0];
    const float* Wih0 = (const float*)d_in[1];
    const float* Whh0 = (const float*)d_in[2];
    const float* bih0 = (const float*)d_in[3];
    const float* bhh0 = (const float*)d_in[4];
    const float* Wih1 = (const float*)d_in[5];
    const float* Whh1 = (const float*)d_in[6];
    const float* bih1 = (const float*)d_in[7];
    const float* bhh1 = (const float*)d_in[8];
    const float* Wfc  = (const float*)d_in[9];
    const float* bfc  = (const float*)d_in[10];

    char* ws = (char*)d_ws;
    size_t off = 0;
    auto alloc = [&](size_t bytes) {
        void* p = ws + off;
        off = (off + bytes + 255) & ~(size_t)255;
        return p;
    };
    ushort* Wc0   = (ushort*)alloc(2048UL * 640 * 2);         // 2.62 MB
    ushort* Wc1   = (ushort*)alloc(2048UL * 1024 * 2);        // 4.19 MB
    float*  bg0   = (float*)alloc(2048 * 4);
    float*  bg1   = (float*)alloc(2048 * 4);
    float*  hlast = (float*)alloc(256UL * 512 * 4);           // 0.52 MB
    ushort* h1par = (ushort*)alloc(2UL * 256 * 512 * 2);      // 0.52 MB
    int*    flags = (int*)alloc(256);
    ushort* h0buf = (ushort*)alloc(256UL * 513 * 512 * 2);    // 134.5 MB
    if (ws_size < off) return;

    hipMemsetAsync(flags, 0, 256, stream);
    init_zeros<<<256, 256, 0, stream>>>(h0buf, h1par);
    cast_w<<<(2048 * 640  + 255) / 256, 256, 0, stream>>>(Wih0, Whh0, Wc0, 128, 640);
    cast_w<<<(2048 * 1024 + 255) / 256, 256, 0, stream>>>(Wih1, Whh1, Wc1, 512, 1024);
    prep_bias<<<8, 256, 0, stream>>>(bih0, bhh0, bih1, bhh1, bg0, bg1);

    {
        void* args0[] = { (void*)&x, (void*)&Wc0, (void*)&bg0, (void*)&h0buf,
                          (void*)&h1par, (void*)&hlast, (void*)&flags };
        hipLaunchCooperativeKernel((const void*)lstm_phase<0>, dim3(256), dim3(512),
                                   args0, 0, stream);
    }
    {
        void* args1[] = { (void*)&x, (void*)&Wc1, (void*)&bg1, (void*)&h0buf,
                          (void*)&h1par, (void*)&hlast, (void*)&flags };
        hipLaunchCooperativeKernel((const void*)lstm_phase<1>, dim3(256), dim3(512),
                                   args1, 0, stream);
    }

    fc_kernel<<<256, 128, 0, stream>>>(hlast, Wfc, bfc, (float*)d_out);
}